// Round 2
// baseline (760.036 us; speedup 1.0000x reference)
//
#include <hip/hip_runtime.h>

// MultiHeadedAttention: out = ((softmax(softmax(QK^T/8)+softmax(mask/128)))V) @ Wo
// Q,K,V (128,512,768) fp32 -> flat [65536][768]. Attention slice (l,h) = rows
// l*128..+127, cols h*64..+63 of the flat projection buffers.
// This round (single variable): attn_k rewritten as a 4-tile-per-block pipeline.
// R1 post-mortem: wave lifetime ~28k cy vs ~1-2k cy of issue work -> latency-
// serial phases, occupancy not the lever. Now: grid (12,128), each block does
// l0..l0+3 with double-buffered K (2x16KB gl_lds) and V^T (2x16KB), wave-local
// 16KB P buffer; V[t+1]/Q[t+1] reg-prefetch + K[t+1] stage issued during tile-t
// compute. ONE s_barrier per tile; ks WAR sealed by staging after the barrier,
// vt WAR by double buffer; single vmcnt(0) at end-of-PV (loads had full compute
// phase to land) avoids fragile counted waits. mm is tile-invariant -> loaded
// once into 32 VGPRs (was 64KB L2 re-read per tile). LDS 80KB -> 2 blocks/CU.
//   convb: fp32->bf16 L3-staging pass. gemm8: cross-phase ds_read prefetch
//   (m196 interleave), vmcnt 6/4/0 drain at ph0. attn compute phases unchanged:
//   swapped QK^T, exp2-folded dual softmax, cvt_pk stores, ps column-halves.

typedef __attribute__((ext_vector_type(8))) __bf16 bf16x8;
typedef __attribute__((ext_vector_type(4))) __bf16 bf16x4;
typedef __attribute__((ext_vector_type(4))) float f32x4;

#define DM 768
#define LOG2E 1.44269504f

__device__ __forceinline__ unsigned short f2bf(float x) {
  unsigned u = __float_as_uint(x);
  u += 0x7FFFu + ((u >> 16) & 1u);   // RNE
  return (unsigned short)(u >> 16);
}

__device__ __forceinline__ void gl_lds16(const void* g, void* l) {
  __builtin_amdgcn_global_load_lds(
      (const __attribute__((address_space(1))) unsigned int*)g,
      (__attribute__((address_space(3))) unsigned int*)l, 16, 0, 0);
}

// ---------------- prep: transpose+convert 4 weights to bf16 [op][n][k] ----------------
__global__ __launch_bounds__(256) void prep_w(const float* __restrict__ w0,
                                              const float* __restrict__ w1,
                                              const float* __restrict__ w2,
                                              const float* __restrict__ w3,
                                              unsigned short* __restrict__ wt) {
  __shared__ float t[32][33];
  const int op = blockIdx.z;
  const float* w = (op == 0) ? w0 : (op == 1) ? w1 : (op == 2) ? w2 : w3;
  unsigned short* o = wt + (size_t)op * DM * DM;
  const int n0 = blockIdx.x * 32, k0 = blockIdx.y * 32;
  const int tx = threadIdx.x & 31, ty = threadIdx.x >> 5;   // ty 0..7
#pragma unroll
  for (int r = 0; r < 4; ++r)
    t[r * 8 + ty][tx] = w[(size_t)(k0 + r * 8 + ty) * DM + n0 + tx];
  __syncthreads();
#pragma unroll
  for (int r = 0; r < 4; ++r)
    o[(size_t)(n0 + r * 8 + ty) * DM + k0 + tx] = f2bf(t[tx][r * 8 + ty]);
}

// ------- prep: mm = softmax(mask/128, axis=-1) * log2e, fp32 [128][128] ---------------
__global__ void prep_m(const float* __restrict__ mask, float* __restrict__ mm) {
  int row = blockIdx.x;
  int t = threadIdx.x;  // 64 threads
  float a = mask[row * 128 + t] * (1.0f / 128.0f);
  float b = mask[row * 128 + t + 64] * (1.0f / 128.0f);
  float mx = fmaxf(a, b);
  for (int s = 1; s < 64; s <<= 1) mx = fmaxf(mx, __shfl_xor(mx, s));
  float ea = __expf(a - mx), eb = __expf(b - mx);
  float sum = ea + eb;
  for (int s = 1; s < 64; s <<= 1) sum += __shfl_xor(sum, s);
  float inv = LOG2E / sum;               // prescale by log2e for attn's exp2 path
  mm[row * 128 + t] = ea * inv;
  mm[row * 128 + t + 64] = eb * inv;
}

// ---------------- conv: fp32 -> bf16, vectorized (8 elems/thread/iter) ----------------
__global__ __launch_bounds__(256) void convb(const float* __restrict__ in,
                                             unsigned short* __restrict__ out, int n8) {
  int i = blockIdx.x * 256 + threadIdx.x;
  const int stride = gridDim.x * 256;
  for (; i < n8; i += stride) {
    const float4 a = ((const float4*)in)[(size_t)i * 2];
    const float4 b = ((const float4*)in)[(size_t)i * 2 + 1];
    ushort4 lo = {f2bf(a.x), f2bf(a.y), f2bf(a.z), f2bf(a.w)};
    ushort4 hi = {f2bf(b.x), f2bf(b.y), f2bf(b.z), f2bf(b.w)};
    ((ushort4*)out)[(size_t)i * 2] = lo;
    ((ushort4*)out)[(size_t)i * 2 + 1] = hi;
  }
}

// ---------------- gemm8: [65536 x 768] bf16 A @ [768 x 768] Bt(n-major bf16) ----------
__device__ __forceinline__ void stage_tile(const unsigned short* __restrict__ src,
                                           int row0, int kcol, char* slotbase, int tid) {
  const int wid = tid >> 6, lane = tid & 63;
#pragma unroll
  for (int s = 0; s < 2; ++s) {
    const int row = s * 128 + wid * 16 + (lane >> 2);
    const int slot = lane & 3;
    gl_lds16(src + (size_t)(row0 + row) * DM + kcol + ((slot ^ ((row >> 1) & 3)) * 8),
             slotbase + s * 8192 + wid * 1024);
  }
}

template <bool OUT_BF16>
__global__ __launch_bounds__(512, 2) void gemm8(const unsigned short* __restrict__ A,
                                                const unsigned short* __restrict__ Bt,
                                                const float* __restrict__ bias,
                                                void* __restrict__ Outp) {
  __shared__ char smem[131072];   // A ring 4x16KB @0, B ring 4x16KB @65536
  const int tid = threadIdx.x, lane = tid & 63, wid = tid >> 6;
  const int cl = lane & 15, g = lane >> 4;
  const int wm = wid >> 2, wn = wid & 3;
  const int bid = blockIdx.x;
  const int xcd = bid & 7, bi = bid >> 3;        // 768 = 8 xcd * (32 m * 3 n)
  const int m0 = (xcd * 32 + bi / 3) * 256;
  const int n0 = (bi % 3) * 256;

  f32x4 acc[8][4] = {};

  auto aslot = [&](int t) { return (char*)smem + (t & 3) * 16384; };
  auto bslot = [&](int t) { return (char*)smem + 65536 + (t & 3) * 16384; };

  auto lda = [&](bf16x8* af, int t, int half) {
#pragma unroll
    for (int mi = 0; mi < 4; ++mi) {
      const int r = wm * 128 + (half * 4 + mi) * 16 + cl;
      af[mi] = *(const bf16x8*)(aslot(t) + r * 64 + ((g ^ ((r >> 1) & 3)) * 16));
    }
  };
  auto ldb = [&](bf16x8* bf, int t) {
#pragma unroll
    for (int ni = 0; ni < 4; ++ni) {
      const int r = wn * 64 + ni * 16 + cl;
      bf[ni] = *(const bf16x8*)(bslot(t) + r * 64 + ((g ^ ((r >> 1) & 3)) * 16));
    }
  };
  auto mfma16 = [&](bf16x8* af, bf16x8* bf, int half) {
    __builtin_amdgcn_s_setprio(1);
#pragma unroll
    for (int mi = 0; mi < 4; ++mi)
#pragma unroll
      for (int ni = 0; ni < 4; ++ni)
        acc[half * 4 + mi][ni] = __builtin_amdgcn_mfma_f32_16x16x32_bf16(
            af[mi], bf[ni], acc[half * 4 + mi][ni], 0, 0, 0);
    __builtin_amdgcn_s_setprio(0);
  };

  // One K-step with cross-phase prefetch. Entering: (af0, bfc) hold step-t frags.
  auto gstep = [&](int t, bool stg, int vm, bf16x8* af0, bf16x8* bfc,
                   bf16x8* af0n, bf16x8* bfn, bool last) {
    bf16x8 af1[4];
    if (stg) stage_tile(A, m0, (t + 3) * 32, aslot(t + 3), tid);
    if (vm == 6)      asm volatile("s_waitcnt vmcnt(6)" ::: "memory");
    else if (vm == 4) asm volatile("s_waitcnt vmcnt(4)" ::: "memory");
    else              asm volatile("s_waitcnt vmcnt(0)" ::: "memory");
    __builtin_amdgcn_s_barrier();
    lda(af1, t, 1);                       // ds reads overlap half0 MFMAs
    mfma16(af0, bfc, 0);
    if (stg) stage_tile(Bt, n0, (t + 3) * 32, bslot(t + 3), tid);
    if (!last) {
      lda(af0n, t + 1, 0);                // ds reads overlap half1 MFMAs
      ldb(bfn, t + 1);
    }
    mfma16(af1, bfc, 1);
    __builtin_amdgcn_s_barrier();
  };

  // prologue: tiles 0,1,2 staged; tile 0 landed; preload step-0 frags.
  stage_tile(A, m0, 0, aslot(0), tid);   stage_tile(Bt, n0, 0, bslot(0), tid);
  stage_tile(A, m0, 32, aslot(1), tid);  stage_tile(Bt, n0, 32, bslot(1), tid);
  stage_tile(A, m0, 64, aslot(2), tid);  stage_tile(Bt, n0, 64, bslot(2), tid);
  asm volatile("s_waitcnt vmcnt(8)" ::: "memory");   // A0,B0 landed
  __builtin_amdgcn_s_barrier();

  bf16x8 afA[4], bfA[4], afB[4], bfB[4];
  lda(afA, 0, 0);
  ldb(bfA, 0);

#pragma unroll 1
  for (int t = 0; t < 20; t += 2) {
    gstep(t, true, 6, afA, bfA, afB, bfB, false);
    gstep(t + 1, true, 6, afB, bfB, afA, bfA, false);
  }
  gstep(20, true, 6, afA, bfA, afB, bfB, false);
  gstep(21, false, 4, afB, bfB, afA, bfA, false);
  gstep(22, false, 0, afA, bfA, afB, bfB, false);
  gstep(23, false, 0, afB, bfB, afA, bfA, true);

  float bb[4];
#pragma unroll
  for (int ni = 0; ni < 4; ++ni) bb[ni] = bias[n0 + wn * 64 + ni * 16 + cl];
#pragma unroll
  for (int mi = 0; mi < 8; ++mi) {
    const int row = m0 + wm * 128 + mi * 16 + g * 4;
#pragma unroll
    for (int ni = 0; ni < 4; ++ni) {
      const int col = n0 + wn * 64 + ni * 16 + cl;
#pragma unroll
      for (int e = 0; e < 4; ++e) {
        float v = acc[mi][ni][e] + bb[ni];
        if constexpr (OUT_BF16)
          ((unsigned short*)Outp)[(size_t)(row + e) * DM + col] = f2bf(v);
        else
          ((float*)Outp)[(size_t)(row + e) * DM + col] = v;
      }
    }
  }
}

// ------------- attention: 4-tile pipelined, 8 waves x 16 q-rows, swapped QK^T ---------
#define TPB 4   // l-tiles per block

__global__ __launch_bounds__(512, 4) void attn_k(const unsigned short* __restrict__ qp,
                                                 const unsigned short* __restrict__ kp,
                                                 const unsigned short* __restrict__ vp,
                                                 const float* __restrict__ mm,
                                                 unsigned short* __restrict__ xout) {
  __shared__ char smem[81920];
  // [0,32768):     ks[2]  two 16KB K buffers [128][64] bf16, 16B-granule XOR
  //                swizzle gi ^= row&7 (gl_lds-staged, linear dest).
  // [32768,65536): vt[2]  two 16KB V^T buffers [64][128] bf16, 4-elem granule
  //                swizzle phys = kq ^ ((d>>3)<<2) (reg-staged transpose).
  // [65536,81920): ps     16KB wave-local P column-half [128][64] bf16,
  //                8B granules gi ^= (q&3)<<2.
  char* psb = smem + 65536;

  const int tid = threadIdx.x, lane = tid & 63, wid = tid >> 6;
  const int cl = lane & 15, g = lane >> 4;
  const int h = blockIdx.x;
  const int l0 = blockIdx.y * TPB;
  const int q = wid * 16 + cl;                   // this lane's q-row

  auto ksb = [&](int t) { return smem + (t & 1) * 16384; };
  auto vtb = [&](int t) { return (unsigned short*)(smem + 32768 + (t & 1) * 16384); };
  auto tbase = [&](int t) { return (size_t)(l0 + t) * 128 * DM + h * 64; };

  // V-transpose mapping (waves 0-3 only): thread handles 4 k-rows x 8 d-cols.
  const bool vw = tid < 256;
  const int dc = (tid & 7) * 8;
  const int kq = (tid & 255) >> 3;
  int4 vr[4];

  auto loadV = [&](size_t base) {
    if (vw) {
#pragma unroll
      for (int r = 0; r < 4; ++r)
        vr[r] = *(const int4*)&vp[base + (size_t)(kq * 4 + r) * DM + dc];
    }
  };
  auto writeVT = [&](unsigned short* vt) {
    if (vw) {
      const int pg = kq ^ ((tid & 7) << 2);
      const unsigned short* u0 = (const unsigned short*)&vr[0];
      const unsigned short* u1 = (const unsigned short*)&vr[1];
      const unsigned short* u2 = (const unsigned short*)&vr[2];
      const unsigned short* u3 = (const unsigned short*)&vr[3];
#pragma unroll
      for (int j = 0; j < 8; ++j) {
        ushort4 w = {u0[j], u1[j], u2[j], u3[j]};
        *(ushort4*)&vt[(dc + j) * 128 + pg * 4] = w;
      }
    }
  };
  auto stageK = [&](size_t base, char* dst) {
#pragma unroll
    for (int p = 0; p < 2; ++p) {
      const int chunk = p * 8 + wid;            // 0..15, 1KB each
      const int row = chunk * 8 + (lane >> 3);  // 128B rows
      const int gi = (lane & 7) ^ (row & 7);
      gl_lds16(kp + base + (size_t)row * DM + gi * 8, dst + chunk * 1024);
    }
  };
  auto loadQ = [&](size_t base, bf16x8* qf) {
#pragma unroll
    for (int ksr = 0; ksr < 2; ++ksr)
      qf[ksr] = *(const bf16x8*)&qp[base + (size_t)q * DM + ksr * 32 + g * 8];
  };

  // ---- prologue: mm rows (tile-invariant, held in regs), V0/Q0 regs, K0 LDS
  float4 mrow[8];
#pragma unroll
  for (int kf = 0; kf < 8; ++kf)
    mrow[kf] = *(const float4*)&mm[q * 128 + kf * 16 + g * 4];

  bf16x8 qfA[2], qfB[2];
  loadV(tbase(0));
  loadQ(tbase(0), qfA);
  stageK(tbase(0), ksb(0));
  asm volatile("s_waitcnt vmcnt(0)" ::: "memory");   // K0 landed (pre-barrier invariant)
  __builtin_amdgcn_sched_barrier(0);

  // ---- one pipelined tile. Entering: V[t],Q[t] in regs (drained), K[t] staged
  // (drained by prev end-of-PV vmcnt(0)).
  auto iter = [&](int t, bool pf, bf16x8* qf, bf16x8* qn) {
    // a) materialize vt[t]; issue V[t+1]/Q[t+1] prefetch (latency hides under
    //    this tile's compute)
    writeVT(vtb(t));
    if (pf) { loadV(tbase(t + 1)); loadQ(tbase(t + 1), qn); }
    asm volatile("s_waitcnt lgkmcnt(0)" ::: "memory");
    __builtin_amdgcn_sched_barrier(0);
    __builtin_amdgcn_s_barrier();   // K[t]+vt[t] visible; seals QK^T[t-1] reads
    // d) stage K[t+1] AFTER the barrier: ksb(t+1) was last read by QK^T[t-1],
    //    which every wave completed before this barrier -> WAR safe.
    if (pf) stageK(tbase(t + 1), ksb(t + 1));

    // f) QK^T[t] from ksb(t)
    f32x4 sacc[8] = {};
    __builtin_amdgcn_s_setprio(1);
#pragma unroll
    for (int ksr = 0; ksr < 2; ++ksr) {
#pragma unroll
      for (int kf = 0; kf < 8; ++kf) {
        const int row = kf * 16 + cl;
        const int gi = (ksr * 4 + g) ^ (row & 7);
        bf16x8 kfr = *(const bf16x8*)(ksb(t) + row * 128 + gi * 16);
        sacc[kf] =
            __builtin_amdgcn_mfma_f32_16x16x32_bf16(kfr, qf[ksr], sacc[kf], 0, 0, 0);
      }
    }
    __builtin_amdgcn_s_setprio(0);

    // g) dual softmax, exp2-folded, no max subtraction (inputs bounded)
    bf16x4 pk[8];
    {
      float sm = 0.f;
#pragma unroll
      for (int kf = 0; kf < 8; ++kf)
#pragma unroll
        for (int e = 0; e < 4; ++e) {
          float p = exp2f(sacc[kf][e] * (0.125f * LOG2E));   // = exp(s/8)
          sacc[kf][e] = p;
          sm += p;
        }
      sm += __shfl_xor(sm, 16); sm += __shfl_xor(sm, 32);
      const float inv2e = LOG2E / sm;
      float s2 = 0.f;
#pragma unroll
      for (int kf = 0; kf < 8; ++kf)
#pragma unroll
        for (int e = 0; e < 4; ++e) {
          // mrow prescaled by log2e: exp(p/sm + m) = exp2(p*inv2e + m*log2e)
          float p = exp2f(fmaf(sacc[kf][e], inv2e, ((const float*)&mrow[kf])[e]));
          sacc[kf][e] = p;
          s2 += p;
        }
      s2 += __shfl_xor(s2, 16); s2 += __shfl_xor(s2, 32);
      const float inv2 = 1.0f / s2;
#pragma unroll
      for (int kf = 0; kf < 8; ++kf)
        pk[kf] = {(__bf16)(sacc[kf][0] * inv2), (__bf16)(sacc[kf][1] * inv2),
                  (__bf16)(sacc[kf][2] * inv2), (__bf16)(sacc[kf][3] * inv2)};
    }

    // h) PV in two column-halves through the wave-local ps buffer.
    f32x4 xacc[4] = {};
    unsigned short* vt = vtb(t);
#pragma unroll
    for (int half = 0; half < 2; ++half) {
#pragma unroll
      for (int kf = 0; kf < 4; ++kf) {
        const int gi = (kf * 4 + g) ^ ((q & 3) << 2);
        *(bf16x4*)(psb + q * 128 + gi * 8) = pk[half * 4 + kf];
      }
      asm volatile("s_waitcnt lgkmcnt(0)" ::: "memory");
      __builtin_amdgcn_sched_barrier(0);
      __builtin_amdgcn_s_setprio(1);
#pragma unroll
      for (int k2 = 0; k2 < 2; ++k2) {
        const int ks2 = half * 2 + k2;
        const int gi = (k2 * 8 + g * 2) ^ ((q & 3) << 2);
        bf16x8 pa = *(const bf16x8*)(psb + q * 128 + gi * 8);
#pragma unroll
        for (int fc = 0; fc < 4; ++fc) {
          const int d = fc * 16 + cl;
          const int pg = (ks2 * 8 + 2 * g) ^ (((d >> 3) & 7) << 2);
          bf16x8 bv = *(const bf16x8*)&vt[d * 128 + pg * 4];
          xacc[fc] = __builtin_amdgcn_mfma_f32_16x16x32_bf16(pa, bv, xacc[fc], 0, 0, 0);
        }
      }
      __builtin_amdgcn_s_setprio(0);
      if (half == 0) {
        asm volatile("s_waitcnt lgkmcnt(0)" ::: "memory");   // half-0 reads drained
        __builtin_amdgcn_sched_barrier(0);
      }
    }

    // end-of-PV drain: K[t+1]/V[t+1]/Q[t+1] had the whole compute phase to
    // land -> near-free; establishes next iter's pre-barrier invariant.
    asm volatile("s_waitcnt vmcnt(0)" ::: "memory");
    __builtin_amdgcn_sched_barrier(0);

    // i) X-store[t]
    const size_t base = tbase(t);
#pragma unroll
    for (int fc = 0; fc < 4; ++fc)
#pragma unroll
      for (int e = 0; e < 4; ++e) {
        const int qr = wid * 16 + g * 4 + e;
        __bf16 b = (__bf16)xacc[fc][e];
        unsigned short u;
        __builtin_memcpy(&u, &b, 2);
        xout[base + (size_t)qr * DM + fc * 16 + cl] = u;
      }
  };

  iter(0, true, qfA, qfB);
  iter(1, true, qfB, qfA);
  iter(2, true, qfA, qfB);
  iter(3, false, qfB, qfA);
}

extern "C" void kernel_launch(void* const* d_in, const int* in_sizes, int n_in,
                              void* d_out, int out_size, void* d_ws, size_t ws_size,
                              hipStream_t stream) {
  (void)in_sizes; (void)n_in; (void)out_size; (void)ws_size;
  const float* Q = (const float*)d_in[0];
  const float* K = (const float*)d_in[1];
  const float* V = (const float*)d_in[2];
  const float* mask = (const float*)d_in[3];
  const float* Wq = (const float*)d_in[4];
  const float* bq = (const float*)d_in[5];
  const float* Wk = (const float*)d_in[6];
  const float* bk = (const float*)d_in[7];
  const float* Wv = (const float*)d_in[8];
  const float* bv = (const float*)d_in[9];
  const float* Wo = (const float*)d_in[10];
  const float* bo = (const float*)d_in[11];

  const size_t NP = (size_t)65536 * DM;   // elements per [65536][768] bf16 buffer

  unsigned short* qp = (unsigned short*)d_out;
  unsigned short* kp = qp + NP;
  unsigned short* S1 = (unsigned short*)d_ws;
  unsigned short* S2 = S1 + NP;
  unsigned short* wt = S2 + NP;                 // [4][768*768] bf16
  float* mm = (float*)(wt + (size_t)4 * DM * DM);

  prep_w<<<dim3(24, 24, 4), 256, 0, stream>>>(Wq, Wk, Wv, Wo, wt);
  prep_m<<<dim3(128), 64, 0, stream>>>(mask, mm);

  const int n8 = (int)(NP / 8);
  dim3 g8(768);

  convb<<<dim3(2048), 256, 0, stream>>>(Q, S1, n8);
  gemm8<true><<<g8, 512, 0, stream>>>(S1, wt + 0 * (size_t)DM * DM, bq, qp);
  convb<<<dim3(2048), 256, 0, stream>>>(K, S1, n8);
  gemm8<true><<<g8, 512, 0, stream>>>(S1, wt + 1 * (size_t)DM * DM, bk, kp);
  convb<<<dim3(2048), 256, 0, stream>>>(V, S2, n8);
  gemm8<true><<<g8, 512, 0, stream>>>(S2, wt + 2 * (size_t)DM * DM, bv, S1);

  attn_k<<<dim3(12, 128), 512, 0, stream>>>(qp, kp, S1, mm, S1);

  gemm8<false><<<g8, 512, 0, stream>>>(S1, wt + 3 * (size_t)DM * DM, bo, (float*)d_out);
}

// Round 3
// 752.089 us; speedup vs baseline: 1.0106x; 1.0106x over previous
//
#include <hip/hip_runtime.h>

// MultiHeadedAttention: out = ((softmax(softmax(QK^T/8)+softmax(mask/128)))V) @ Wo
// Q,K,V (128,512,768) fp32 -> flat [65536][768]. Attention slice (l,h) = rows
// l*128..+127, cols h*64..+63 of the flat projection buffers.
// R2 post-mortem: in-block tile pipelining destroyed cross-block overlap and
// L2 write coalescing (traffic 252->685 MB, attn 123->213us). Reverted attn to
// the R1 structure (grid (12,512), 32KB LDS, ~123us).
// This round (single variable): FUSE the fp32->bf16 conversion into gemm8's
// A-staging and DELETE the 3 convb passes (~145us of pure conversion traffic).
// A-tiles reg-staged: load 16 fp32/thread for tile t+3 at ph0, cvt+ds_write
// tile t+2 late-step (2-step ~1000cy budget > 900cy HBM) into the IDENTICAL
// swizzled LDS layout -> lda/mfma/B-path untouched. vmcnt recounted: steady 10,
// tail 6/0; prologue 8/6 with issue order arranged so each wait drains exactly
// its target. Two named float4[4] reg buffers alternated by parity (rule #20).
// Wo-gemm keeps the proven bf16-A path (if constexpr).

typedef __attribute__((ext_vector_type(8))) __bf16 bf16x8;
typedef __attribute__((ext_vector_type(4))) __bf16 bf16x4;
typedef __attribute__((ext_vector_type(4))) float f32x4;

#define DM 768
#define LOG2E 1.44269504f

__device__ __forceinline__ unsigned short f2bf(float x) {
  unsigned u = __float_as_uint(x);
  u += 0x7FFFu + ((u >> 16) & 1u);   // RNE
  return (unsigned short)(u >> 16);
}

__device__ __forceinline__ void gl_lds16(const void* g, void* l) {
  __builtin_amdgcn_global_load_lds(
      (const __attribute__((address_space(1))) unsigned int*)g,
      (__attribute__((address_space(3))) unsigned int*)l, 16, 0, 0);
}

__device__ __forceinline__ void waitvm(int n) {
  switch (n) {
    case 0:  asm volatile("s_waitcnt vmcnt(0)" ::: "memory"); break;
    case 2:  asm volatile("s_waitcnt vmcnt(2)" ::: "memory"); break;
    case 4:  asm volatile("s_waitcnt vmcnt(4)" ::: "memory"); break;
    case 6:  asm volatile("s_waitcnt vmcnt(6)" ::: "memory"); break;
    case 8:  asm volatile("s_waitcnt vmcnt(8)" ::: "memory"); break;
    default: asm volatile("s_waitcnt vmcnt(10)" ::: "memory"); break;
  }
}

// ---------------- prep: transpose+convert 4 weights to bf16 [op][n][k] ----------------
__global__ __launch_bounds__(256) void prep_w(const float* __restrict__ w0,
                                              const float* __restrict__ w1,
                                              const float* __restrict__ w2,
                                              const float* __restrict__ w3,
                                              unsigned short* __restrict__ wt) {
  __shared__ float t[32][33];
  const int op = blockIdx.z;
  const float* w = (op == 0) ? w0 : (op == 1) ? w1 : (op == 2) ? w2 : w3;
  unsigned short* o = wt + (size_t)op * DM * DM;
  const int n0 = blockIdx.x * 32, k0 = blockIdx.y * 32;
  const int tx = threadIdx.x & 31, ty = threadIdx.x >> 5;   // ty 0..7
#pragma unroll
  for (int r = 0; r < 4; ++r)
    t[r * 8 + ty][tx] = w[(size_t)(k0 + r * 8 + ty) * DM + n0 + tx];
  __syncthreads();
#pragma unroll
  for (int r = 0; r < 4; ++r)
    o[(size_t)(n0 + r * 8 + ty) * DM + k0 + tx] = f2bf(t[tx][r * 8 + ty]);
}

// ------- prep: mm = softmax(mask/128, axis=-1) * log2e, fp32 [128][128] ---------------
__global__ void prep_m(const float* __restrict__ mask, float* __restrict__ mm) {
  int row = blockIdx.x;
  int t = threadIdx.x;  // 64 threads
  float a = mask[row * 128 + t] * (1.0f / 128.0f);
  float b = mask[row * 128 + t + 64] * (1.0f / 128.0f);
  float mx = fmaxf(a, b);
  for (int s = 1; s < 64; s <<= 1) mx = fmaxf(mx, __shfl_xor(mx, s));
  float ea = __expf(a - mx), eb = __expf(b - mx);
  float sum = ea + eb;
  for (int s = 1; s < 64; s <<= 1) sum += __shfl_xor(sum, s);
  float inv = LOG2E / sum;               // prescale by log2e for attn's exp2 path
  mm[row * 128 + t] = ea * inv;
  mm[row * 128 + t + 64] = eb * inv;
}

// ---------------- gemm8: [65536 x 768] A @ [768 x 768] Bt(n-major bf16) ---------------
// A is bf16 (A_FP32=false, gl_lds-staged) or fp32 (A_FP32=true, reg-staged with
// fused cvt into the same swizzled LDS layout).
__device__ __forceinline__ void stage_tile(const unsigned short* __restrict__ src,
                                           int row0, int kcol, char* slotbase, int tid) {
  const int wid = tid >> 6, lane = tid & 63;
#pragma unroll
  for (int s = 0; s < 2; ++s) {
    const int row = s * 128 + wid * 16 + (lane >> 2);
    const int slot = lane & 3;
    gl_lds16(src + (size_t)(row0 + row) * DM + kcol + ((slot ^ ((row >> 1) & 3)) * 8),
             slotbase + s * 8192 + wid * 1024);
  }
}

template <bool OUT_BF16, bool A_FP32>
__global__ __launch_bounds__(512, 2) void gemm8(const void* __restrict__ Ap,
                                                const unsigned short* __restrict__ Bt,
                                                const float* __restrict__ bias,
                                                void* __restrict__ Outp) {
  __shared__ char smem[131072];   // A ring 4x16KB @0, B ring 4x16KB @65536
  const unsigned short* A16 = (const unsigned short*)Ap;
  const float* A32 = (const float*)Ap;
  const int tid = threadIdx.x, lane = tid & 63, wid = tid >> 6;
  const int cl = lane & 15, g = lane >> 4;
  const int wm = wid >> 2, wn = wid & 3;
  const int bid = blockIdx.x;
  const int xcd = bid & 7, bi = bid >> 3;        // 768 = 8 xcd * (32 m * 3 n)
  const int m0 = (xcd * 32 + bi / 3) * 256;
  const int n0 = (bi % 3) * 256;

  f32x4 acc[8][4] = {};

  auto aslot = [&](int t) { return (char*)smem + (t & 3) * 16384; };
  auto bslot = [&](int t) { return (char*)smem + 65536 + (t & 3) * 16384; };

  // --- fused-conversion A reg-staging (A_FP32 only) ---
  const int arow = tid >> 1, ahalf = tid & 1;    // row 0..255, col-half 0/1
  float4 ar0[4], ar1[4];                         // two named buffers (rule #20)
  auto aloadR = [&](int t, float4* buf) {        // issue 4 float4 loads, tile t
    const float* src = &A32[(size_t)(m0 + arow) * DM + t * 32 + ahalf * 16];
#pragma unroll
    for (int i = 0; i < 4; ++i) buf[i] = *(const float4*)(src + i * 4);
  };
  auto awrite = [&](int t, const float4* buf) {  // cvt + ds_write tile t
    const float* f = (const float*)buf;
    bf16x8 v0, v1;
#pragma unroll
    for (int j = 0; j < 8; ++j) {
      v0[j] = (__bf16)f[j];
      v1[j] = (__bf16)f[8 + j];
    }
    const int m = (arow >> 1) & 3;
    const int s0 = (ahalf * 2) ^ m;              // slot of colgroup cg: cg ^ m
    char* base = aslot(t) + arow * 64;
    *(bf16x8*)(base + s0 * 16) = v0;
    *(bf16x8*)(base + (s0 ^ 1) * 16) = v1;       // cg even -> slots pair up
  };

  auto lda = [&](bf16x8* af, int t, int half) {
#pragma unroll
    for (int mi = 0; mi < 4; ++mi) {
      const int r = wm * 128 + (half * 4 + mi) * 16 + cl;
      af[mi] = *(const bf16x8*)(aslot(t) + r * 64 + ((g ^ ((r >> 1) & 3)) * 16));
    }
  };
  auto ldb = [&](bf16x8* bf, int t) {
#pragma unroll
    for (int ni = 0; ni < 4; ++ni) {
      const int r = wn * 64 + ni * 16 + cl;
      bf[ni] = *(const bf16x8*)(bslot(t) + r * 64 + ((g ^ ((r >> 1) & 3)) * 16));
    }
  };
  auto mfma16 = [&](bf16x8* af, bf16x8* bf, int half) {
    __builtin_amdgcn_s_setprio(1);
#pragma unroll
    for (int mi = 0; mi < 4; ++mi)
#pragma unroll
      for (int ni = 0; ni < 4; ++ni)
        acc[half * 4 + mi][ni] = __builtin_amdgcn_mfma_f32_16x16x32_bf16(
            af[mi], bf[ni], acc[half * 4 + mi][ni], 0, 0, 0);
    __builtin_amdgcn_s_setprio(0);
  };

  // One K-step with cross-phase prefetch. Entering: (af0, bfc) hold step-t frags.
  // A_FP32 steady state outstanding at ph0 (after load issue):
  //   [B(t+1)2, A(t+2)4, B(t+2)2, A(t+3)4] = 12 -> vm=10 drains B(t+1) exactly.
  // Late-step awrite(t+2) consumes regs loaded at t-1 ph0 (~2-step budget);
  // compiler auto-waitcnt guards the reg reads; lgkm(0) seals ds_writes before
  // the end barrier (consumers read at t+2 after 2 barriers).
  auto gstep = [&](int t, bool stg, int vm, bool wr, float4* arL, float4* arW,
                   bf16x8* af0, bf16x8* bfc, bf16x8* af0n, bf16x8* bfn, bool last) {
    bf16x8 af1[4];
    if constexpr (A_FP32) {
      if (stg) aloadR(t + 3, arL);
    } else {
      if (stg) stage_tile(A16, m0, (t + 3) * 32, aslot(t + 3), tid);
    }
    waitvm(vm);
    __builtin_amdgcn_s_barrier();
    lda(af1, t, 1);                       // ds reads overlap half0 MFMAs
    mfma16(af0, bfc, 0);
    if (stg) stage_tile(Bt, n0, (t + 3) * 32, bslot(t + 3), tid);
    if (!last) {
      lda(af0n, t + 1, 0);                // ds reads overlap half1 MFMAs
      ldb(bfn, t + 1);
    }
    mfma16(af1, bfc, 1);
    if constexpr (A_FP32) {
      if (wr) {
        awrite(t + 2, arW);
        asm volatile("s_waitcnt lgkmcnt(0)" ::: "memory");
        __builtin_amdgcn_sched_barrier(0);
      }
    }
    __builtin_amdgcn_s_barrier();
  };

  // ---- prologue: aslot(0,1) written, B(0,1,2) staged, regs hold A(2).
  if constexpr (A_FP32) {
    aloadR(0, ar0);
    stage_tile(Bt, n0, 0, bslot(0), tid);
    aloadR(1, ar1);
    stage_tile(Bt, n0, 32, bslot(1), tid);
    waitvm(8);            // [A0 4,B0 2,A1 4,B1 2]=12 -> drain A0
    awrite(0, ar0);
    aloadR(2, ar0);
    waitvm(6);            // [B0 2,A1 4,B1 2,A2 4]=12 -> drain B0,A1
    awrite(1, ar1);
    stage_tile(Bt, n0, 64, bslot(2), tid);
    // leaves [B1 2, A2 4, B2 2] = 8 -> matches steady-state entry for t=0
    asm volatile("s_waitcnt lgkmcnt(0)" ::: "memory");
    __builtin_amdgcn_sched_barrier(0);
    __builtin_amdgcn_s_barrier();
  } else {
    stage_tile(A16, m0, 0, aslot(0), tid);  stage_tile(Bt, n0, 0, bslot(0), tid);
    stage_tile(A16, m0, 32, aslot(1), tid); stage_tile(Bt, n0, 32, bslot(1), tid);
    stage_tile(A16, m0, 64, aslot(2), tid); stage_tile(Bt, n0, 64, bslot(2), tid);
    asm volatile("s_waitcnt vmcnt(8)" ::: "memory");   // A0,B0 landed
    __builtin_amdgcn_s_barrier();
  }

  bf16x8 afA[4], bfA[4], afB[4], bfB[4];
  lda(afA, 0, 0);
  ldb(bfA, 0);

  constexpr int VMs = A_FP32 ? 10 : 6;   // steady-state ph0 drain
#pragma unroll 1
  for (int t = 0; t < 20; t += 2) {
    gstep(t, true, VMs, true, ar1, ar0, afA, bfA, afB, bfB, false);
    gstep(t + 1, true, VMs, true, ar0, ar1, afB, bfB, afA, bfA, false);
  }
  if constexpr (A_FP32) {
    gstep(20, true, 10, true, ar1, ar0, afA, bfA, afB, bfB, false);
    gstep(21, false, 6, true, ar0, ar1, afB, bfB, afA, bfA, false);  // writes A23
    gstep(22, false, 0, false, ar1, ar0, afA, bfA, afB, bfB, false);
    gstep(23, false, 0, false, ar0, ar1, afB, bfB, afA, bfA, true);
  } else {
    gstep(20, true, 6, false, ar1, ar0, afA, bfA, afB, bfB, false);
    gstep(21, false, 4, false, ar0, ar1, afB, bfB, afA, bfA, false);
    gstep(22, false, 0, false, ar1, ar0, afA, bfA, afB, bfB, false);
    gstep(23, false, 0, false, ar0, ar1, afB, bfB, afA, bfA, true);
  }

  float bb[4];
#pragma unroll
  for (int ni = 0; ni < 4; ++ni) bb[ni] = bias[n0 + wn * 64 + ni * 16 + cl];
#pragma unroll
  for (int mi = 0; mi < 8; ++mi) {
    const int row = m0 + wm * 128 + mi * 16 + g * 4;
#pragma unroll
    for (int ni = 0; ni < 4; ++ni) {
      const int col = n0 + wn * 64 + ni * 16 + cl;
#pragma unroll
      for (int e = 0; e < 4; ++e) {
        float v = acc[mi][ni][e] + bb[ni];
        if constexpr (OUT_BF16)
          ((unsigned short*)Outp)[(size_t)(row + e) * DM + col] = f2bf(v);
        else
          ((float*)Outp)[(size_t)(row + e) * DM + col] = v;
      }
    }
  }
}

// ---------------- attention: 8 waves x 16 q-rows, swapped QK^T, exp2 softmax ----------
__global__ __launch_bounds__(512) void attn_k(const unsigned short* __restrict__ qp,
                                              const unsigned short* __restrict__ kp,
                                              const unsigned short* __restrict__ vp,
                                              const float* __restrict__ mm,
                                              unsigned short* __restrict__ xout) {
  __shared__ char smem[32768];
  // [0,16384): ks [128][64] bf16, 16B-granule XOR swizzle (gi ^= row&7); after
  //            the post-QK^T barrier, reused as ps [128][64] bf16 COLUMN-HALF
  //            of P (two passes: cols 0..63 then 64..127), 8B granules,
  //            gi ^= (q&3)<<2.
  // [16384,32768): vt [64][128] bf16, 4-elem granule swizzle: phys = kq ^ ((d>>3)<<2)
  unsigned short* vt = (unsigned short*)(smem + 16384);

  const int tid = threadIdx.x, lane = tid & 63, wid = tid >> 6;
  const int cl = lane & 15, g = lane >> 4;
  const int h = blockIdx.x, l = blockIdx.y;
  const size_t base = (size_t)l * 128 * DM + h * 64;
  const int q = wid * 16 + cl;                   // this lane's q-row

#pragma unroll
  for (int p = 0; p < 2; ++p) {
    const int chunk = p * 8 + wid;              // 0..15, 1KB each
    const int row = chunk * 8 + (lane >> 3);    // 128B rows
    const int gi = (lane & 7) ^ (row & 7);
    gl_lds16(kp + base + (size_t)row * DM + gi * 8, smem + chunk * 1024);
  }
  if (tid < 256) {
    const int dc = (tid & 7) * 8;
    const int kq = tid >> 3;
    const int pg = (kq ^ ((tid & 7) << 2));
    int4 r0 = *(const int4*)&vp[base + (size_t)(kq * 4 + 0) * DM + dc];
    int4 r1 = *(const int4*)&vp[base + (size_t)(kq * 4 + 1) * DM + dc];
    int4 r2 = *(const int4*)&vp[base + (size_t)(kq * 4 + 2) * DM + dc];
    int4 r3 = *(const int4*)&vp[base + (size_t)(kq * 4 + 3) * DM + dc];
    const unsigned short* u0 = (const unsigned short*)&r0;
    const unsigned short* u1 = (const unsigned short*)&r1;
    const unsigned short* u2 = (const unsigned short*)&r2;
    const unsigned short* u3 = (const unsigned short*)&r3;
#pragma unroll
    for (int j = 0; j < 8; ++j) {
      ushort4 w = {u0[j], u1[j], u2[j], u3[j]};
      *(ushort4*)&vt[(dc + j) * 128 + pg * 4] = w;
    }
  }
  bf16x8 qf[2];
#pragma unroll
  for (int ksr = 0; ksr < 2; ++ksr)
    qf[ksr] = *(const bf16x8*)&qp[base + (size_t)q * DM + ksr * 32 + g * 8];
  __syncthreads();

  f32x4 sacc[8] = {};
  __builtin_amdgcn_s_setprio(1);
#pragma unroll
  for (int ksr = 0; ksr < 2; ++ksr) {
#pragma unroll
    for (int kf = 0; kf < 8; ++kf) {
      const int row = kf * 16 + cl;
      const int gi = (ksr * 4 + g) ^ (row & 7);
      bf16x8 kfr = *(const bf16x8*)(smem + row * 128 + gi * 16);
      sacc[kf] = __builtin_amdgcn_mfma_f32_16x16x32_bf16(kfr, qf[ksr], sacc[kf], 0, 0, 0);
    }
  }
  __builtin_amdgcn_s_setprio(0);
  __syncthreads();   // all waves' ks reads done before any ps write (ps aliases ks)

  // ---- dual softmax, exp2-folded, no max subtraction (inputs bounded)
  bf16x4 pk[8];
  {
    float4 mrow[8];
#pragma unroll
    for (int kf = 0; kf < 8; ++kf)
      mrow[kf] = *(const float4*)&mm[q * 128 + kf * 16 + g * 4];
    float sm = 0.f;
#pragma unroll
    for (int kf = 0; kf < 8; ++kf)
#pragma unroll
      for (int e = 0; e < 4; ++e) {
        float p = exp2f(sacc[kf][e] * (0.125f * LOG2E));   // = exp(s/8)
        sacc[kf][e] = p;
        sm += p;
      }
    sm += __shfl_xor(sm, 16); sm += __shfl_xor(sm, 32);
    const float inv2e = LOG2E / sm;
    float s2 = 0.f;
#pragma unroll
    for (int kf = 0; kf < 8; ++kf)
#pragma unroll
      for (int e = 0; e < 4; ++e) {
        // mrow prescaled by log2e: exp(p/sm + m) = exp2(p*inv2e + m*log2e)
        float p = exp2f(fmaf(sacc[kf][e], inv2e, ((const float*)&mrow[kf])[e]));
        sacc[kf][e] = p;
        s2 += p;
      }
    s2 += __shfl_xor(s2, 16); s2 += __shfl_xor(s2, 32);
    const float inv2 = 1.0f / s2;
#pragma unroll
    for (int kf = 0; kf < 8; ++kf)
      pk[kf] = {(__bf16)(sacc[kf][0] * inv2), (__bf16)(sacc[kf][1] * inv2),
                (__bf16)(sacc[kf][2] * inv2), (__bf16)(sacc[kf][3] * inv2)};
  }

  // ---- PV in two column-halves through the 16KB ps buffer (wave-local rows;
  // lgkm fences only, no block barrier; rule #18 sched_barrier after each).
  f32x4 xacc[4] = {};
#pragma unroll
  for (int half = 0; half < 2; ++half) {
#pragma unroll
    for (int kf = 0; kf < 4; ++kf) {
      const int gi = (kf * 4 + g) ^ ((q & 3) << 2);
      *(bf16x4*)(smem + q * 128 + gi * 8) = pk[half * 4 + kf];
    }
    asm volatile("s_waitcnt lgkmcnt(0)" ::: "memory");
    __builtin_amdgcn_sched_barrier(0);
    __builtin_amdgcn_s_setprio(1);
#pragma unroll
    for (int k2 = 0; k2 < 2; ++k2) {
      const int ks2 = half * 2 + k2;
      const int gi = (k2 * 8 + g * 2) ^ ((q & 3) << 2);
      bf16x8 pa = *(const bf16x8*)(smem + q * 128 + gi * 8);
#pragma unroll
      for (int fc = 0; fc < 4; ++fc) {
        const int d = fc * 16 + cl;
        const int pg = (ks2 * 8 + 2 * g) ^ (((d >> 3) & 7) << 2);
        bf16x8 bv = *(const bf16x8*)&vt[d * 128 + pg * 4];
        xacc[fc] = __builtin_amdgcn_mfma_f32_16x16x32_bf16(pa, bv, xacc[fc], 0, 0, 0);
      }
    }
    __builtin_amdgcn_s_setprio(0);
    if (half == 0) {
      asm volatile("s_waitcnt lgkmcnt(0)" ::: "memory");   // half-0 reads drained
      __builtin_amdgcn_sched_barrier(0);
    }
  }

  // X-store via plain casts (compiler cvt_pk where possible)
#pragma unroll
  for (int fc = 0; fc < 4; ++fc)
#pragma unroll
    for (int e = 0; e < 4; ++e) {
      const int qr = wid * 16 + g * 4 + e;
      __bf16 b = (__bf16)xacc[fc][e];
      unsigned short u;
      __builtin_memcpy(&u, &b, 2);
      xout[base + (size_t)qr * DM + fc * 16 + cl] = u;
    }
}

extern "C" void kernel_launch(void* const* d_in, const int* in_sizes, int n_in,
                              void* d_out, int out_size, void* d_ws, size_t ws_size,
                              hipStream_t stream) {
  (void)in_sizes; (void)n_in; (void)out_size; (void)ws_size;
  const float* Q = (const float*)d_in[0];
  const float* K = (const float*)d_in[1];
  const float* V = (const float*)d_in[2];
  const float* mask = (const float*)d_in[3];
  const float* Wq = (const float*)d_in[4];
  const float* bq = (const float*)d_in[5];
  const float* Wk = (const float*)d_in[6];
  const float* bk = (const float*)d_in[7];
  const float* Wv = (const float*)d_in[8];
  const float* bv = (const float*)d_in[9];
  const float* Wo = (const float*)d_in[10];
  const float* bo = (const float*)d_in[11];

  const size_t NP = (size_t)65536 * DM;   // elements per [65536][768] bf16 buffer

  unsigned short* qp = (unsigned short*)d_out;
  unsigned short* kp = qp + NP;
  unsigned short* S1 = (unsigned short*)d_ws;   // V-proj, then attn X (aliased on purpose)
  unsigned short* wt = S1 + NP;                 // [4][768*768] bf16
  float* mm = (float*)(wt + (size_t)4 * DM * DM);

  prep_w<<<dim3(24, 24, 4), 256, 0, stream>>>(Wq, Wk, Wv, Wo, wt);
  prep_m<<<dim3(128), 64, 0, stream>>>(mask, mm);

  dim3 g8(768);

  // fused fp32->bf16 A-staging: no convb passes
  gemm8<true, true><<<g8, 512, 0, stream>>>(Q, wt + 0 * (size_t)DM * DM, bq, qp);
  gemm8<true, true><<<g8, 512, 0, stream>>>(K, wt + 1 * (size_t)DM * DM, bk, kp);
  gemm8<true, true><<<g8, 512, 0, stream>>>(V, wt + 2 * (size_t)DM * DM, bv, S1);

  attn_k<<<dim3(12, 512), 512, 0, stream>>>(qp, kp, S1, mm, S1);

  gemm8<false, false><<<g8, 512, 0, stream>>>(S1, wt + 3 * (size_t)DM * DM, bo,
                                              (float*)d_out);
}

// Round 4
// 734.439 us; speedup vs baseline: 1.0349x; 1.0240x over previous
//
#include <hip/hip_runtime.h>

// MultiHeadedAttention: out = ((softmax(softmax(QK^T/8)+softmax(mask/128)))V) @ Wo
// Q,K,V (128,512,768) fp32 -> flat [65536][768]. Attention slice (l,h) = rows
// l*128..+127, cols h*64..+63 of the flat projection buffers.
// R3 post-mortem: fused fp32 A-staging regressed (reg-load->ds_write distance
// 1.5 steps < HBM latency; and the register file pins gemm8 at 8 waves/CU:
// acc 128 + arch 128 = 256/wave -> occupancy is structurally capped, stalls
// must be fixed IN-schedule). Reverted to convb + bf16-A gemm.
// This round (single variable): halve gemm8's sync-event count. K-steps are
// PAIRED: each double-step stages tiles {u+2,u+3} (8 ops), ONE vmcnt(8) (drains
// {u,u+1}, keeps 8 ops in flight -> same ~700cy latency gap as before), one
// entry barrier, 128 MFMAs (4 clusters of 32, cross-cluster ds_read prefetch,
// frag buffers reused), one exit barrier. 48 -> 26 sync events per block.
// LDS layout / swizzles / frag math byte-identical to the proven R1 kernel.
//   attn: R1-proven (32KB, ps column-halves, exp2-folded dual softmax, 123us).

typedef __attribute__((ext_vector_type(8))) __bf16 bf16x8;
typedef __attribute__((ext_vector_type(4))) __bf16 bf16x4;
typedef __attribute__((ext_vector_type(4))) float f32x4;

#define DM 768
#define LOG2E 1.44269504f

__device__ __forceinline__ unsigned short f2bf(float x) {
  unsigned u = __float_as_uint(x);
  u += 0x7FFFu + ((u >> 16) & 1u);   // RNE
  return (unsigned short)(u >> 16);
}

__device__ __forceinline__ void gl_lds16(const void* g, void* l) {
  __builtin_amdgcn_global_load_lds(
      (const __attribute__((address_space(1))) unsigned int*)g,
      (__attribute__((address_space(3))) unsigned int*)l, 16, 0, 0);
}

// ---------------- prep: transpose+convert 4 weights to bf16 [op][n][k] ----------------
__global__ __launch_bounds__(256) void prep_w(const float* __restrict__ w0,
                                              const float* __restrict__ w1,
                                              const float* __restrict__ w2,
                                              const float* __restrict__ w3,
                                              unsigned short* __restrict__ wt) {
  __shared__ float t[32][33];
  const int op = blockIdx.z;
  const float* w = (op == 0) ? w0 : (op == 1) ? w1 : (op == 2) ? w2 : w3;
  unsigned short* o = wt + (size_t)op * DM * DM;
  const int n0 = blockIdx.x * 32, k0 = blockIdx.y * 32;
  const int tx = threadIdx.x & 31, ty = threadIdx.x >> 5;   // ty 0..7
#pragma unroll
  for (int r = 0; r < 4; ++r)
    t[r * 8 + ty][tx] = w[(size_t)(k0 + r * 8 + ty) * DM + n0 + tx];
  __syncthreads();
#pragma unroll
  for (int r = 0; r < 4; ++r)
    o[(size_t)(n0 + r * 8 + ty) * DM + k0 + tx] = f2bf(t[tx][r * 8 + ty]);
}

// ------- prep: mm = softmax(mask/128, axis=-1) * log2e, fp32 [128][128] ---------------
__global__ void prep_m(const float* __restrict__ mask, float* __restrict__ mm) {
  int row = blockIdx.x;
  int t = threadIdx.x;  // 64 threads
  float a = mask[row * 128 + t] * (1.0f / 128.0f);
  float b = mask[row * 128 + t + 64] * (1.0f / 128.0f);
  float mx = fmaxf(a, b);
  for (int s = 1; s < 64; s <<= 1) mx = fmaxf(mx, __shfl_xor(mx, s));
  float ea = __expf(a - mx), eb = __expf(b - mx);
  float sum = ea + eb;
  for (int s = 1; s < 64; s <<= 1) sum += __shfl_xor(sum, s);
  float inv = LOG2E / sum;               // prescale by log2e for attn's exp2 path
  mm[row * 128 + t] = ea * inv;
  mm[row * 128 + t + 64] = eb * inv;
}

// ---------------- conv: fp32 -> bf16, vectorized (8 elems/thread/iter) ----------------
__global__ __launch_bounds__(256) void convb(const float* __restrict__ in,
                                             unsigned short* __restrict__ out, int n8) {
  int i = blockIdx.x * 256 + threadIdx.x;
  const int stride = gridDim.x * 256;
  for (; i < n8; i += stride) {
    const float4 a = ((const float4*)in)[(size_t)i * 2];
    const float4 b = ((const float4*)in)[(size_t)i * 2 + 1];
    ushort4 lo = {f2bf(a.x), f2bf(a.y), f2bf(a.z), f2bf(a.w)};
    ushort4 hi = {f2bf(b.x), f2bf(b.y), f2bf(b.z), f2bf(b.w)};
    ((ushort4*)out)[(size_t)i * 2] = lo;
    ((ushort4*)out)[(size_t)i * 2 + 1] = hi;
  }
}

// ---------------- gemm8: [65536 x 768] bf16 A @ [768 x 768] Bt(n-major bf16) ----------
__device__ __forceinline__ void stage_tile(const unsigned short* __restrict__ src,
                                           int row0, int kcol, char* slotbase, int tid) {
  const int wid = tid >> 6, lane = tid & 63;
#pragma unroll
  for (int s = 0; s < 2; ++s) {
    const int row = s * 128 + wid * 16 + (lane >> 2);
    const int slot = lane & 3;
    gl_lds16(src + (size_t)(row0 + row) * DM + kcol + ((slot ^ ((row >> 1) & 3)) * 8),
             slotbase + s * 8192 + wid * 1024);
  }
}

template <bool OUT_BF16>
__global__ __launch_bounds__(512, 2) void gemm8(const unsigned short* __restrict__ A,
                                                const unsigned short* __restrict__ Bt,
                                                const float* __restrict__ bias,
                                                void* __restrict__ Outp) {
  __shared__ char smem[131072];   // A ring 4x16KB @0, B ring 4x16KB @65536
  const int tid = threadIdx.x, lane = tid & 63, wid = tid >> 6;
  const int cl = lane & 15, g = lane >> 4;
  const int wm = wid >> 2, wn = wid & 3;
  const int bid = blockIdx.x;
  const int xcd = bid & 7, bi = bid >> 3;        // 768 = 8 xcd * (32 m * 3 n)
  const int m0 = (xcd * 32 + bi / 3) * 256;
  const int n0 = (bi % 3) * 256;

  f32x4 acc[8][4] = {};

  auto aslot = [&](int t) { return (char*)smem + (t & 3) * 16384; };
  auto bslot = [&](int t) { return (char*)smem + 65536 + (t & 3) * 16384; };

  auto lda = [&](bf16x8* af, int t, int half) {
#pragma unroll
    for (int mi = 0; mi < 4; ++mi) {
      const int r = wm * 128 + (half * 4 + mi) * 16 + cl;
      af[mi] = *(const bf16x8*)(aslot(t) + r * 64 + ((g ^ ((r >> 1) & 3)) * 16));
    }
  };
  auto ldb = [&](bf16x8* bf, int t) {
#pragma unroll
    for (int ni = 0; ni < 4; ++ni) {
      const int r = wn * 64 + ni * 16 + cl;
      bf[ni] = *(const bf16x8*)(bslot(t) + r * 64 + ((g ^ ((r >> 1) & 3)) * 16));
    }
  };
  auto mfma16 = [&](bf16x8* af, bf16x8* bf, int half) {
    __builtin_amdgcn_s_setprio(1);
#pragma unroll
    for (int mi = 0; mi < 4; ++mi)
#pragma unroll
      for (int ni = 0; ni < 4; ++ni)
        acc[half * 4 + mi][ni] = __builtin_amdgcn_mfma_f32_16x16x32_bf16(
            af[mi], bf[ni], acc[half * 4 + mi][ni], 0, 0, 0);
    __builtin_amdgcn_s_setprio(0);
  };

  auto stg2 = [&](int u) {   // stage K32-tile u (A 2 ops + B 2 ops)
    stage_tile(A, m0, u * 32, aslot(u), tid);
    stage_tile(Bt, n0, u * 32, bslot(u), tid);
  };

  // ---- prologue: tiles 0,1 staged + landed.
  stg2(0); stg2(1);
  asm volatile("s_waitcnt vmcnt(0)" ::: "memory");
  __builtin_amdgcn_s_barrier();

  bf16x8 afA[4], af1[4], afB[4], bfA[4], bfB[4];

  // ---- 12 double-steps, each covering K32-tiles {u, u+1}. Sync events per
  // double-step: 1 vm-wait + 2 barriers (was 2 vm-waits + 4 barriers for the
  // same K-range). Staging {u+2,u+3} overwrites slots of {u-2,u-1}, whose
  // reads were sealed by the previous exit barrier (WAR safe). vmcnt(8) keeps
  // the 8 just-issued ops in flight (~700cy gap to their consumption).
#pragma unroll 1
  for (int t = 0; t < 12; ++t) {
    const int u = 2 * t;
    if (t < 11) {
      stg2(u + 2); stg2(u + 3);
      asm volatile("s_waitcnt vmcnt(8)" ::: "memory");   // {u,u+1} landed
    } else {
      asm volatile("s_waitcnt vmcnt(0)" ::: "memory");   // {22,23} landed
    }
    __builtin_amdgcn_s_barrier();
    // 4 MFMA clusters with cross-cluster ds_read prefetch; frag regs reused
    // (afA dies after c0, af1 after c1 -> live frags stay ~20 = 80 VGPR).
    lda(afA, u, 0); ldb(bfA, u);
    lda(af1, u, 1);                       // c1 frags overlap c0 MFMAs
    mfma16(afA, bfA, 0);                  // c0
    lda(afB, u + 1, 0); ldb(bfB, u + 1);  // c2 frags overlap c1 MFMAs
    mfma16(af1, bfA, 1);                  // c1
    lda(afA, u + 1, 1);                   // c3 frags overlap c2 MFMAs
    mfma16(afB, bfB, 0);                  // c2
    mfma16(afA, bfB, 1);                  // c3
    __builtin_amdgcn_s_barrier();
  }

  float bb[4];
#pragma unroll
  for (int ni = 0; ni < 4; ++ni) bb[ni] = bias[n0 + wn * 64 + ni * 16 + cl];
#pragma unroll
  for (int mi = 0; mi < 8; ++mi) {
    const int row = m0 + wm * 128 + mi * 16 + g * 4;
#pragma unroll
    for (int ni = 0; ni < 4; ++ni) {
      const int col = n0 + wn * 64 + ni * 16 + cl;
#pragma unroll
      for (int e = 0; e < 4; ++e) {
        float v = acc[mi][ni][e] + bb[ni];
        if constexpr (OUT_BF16)
          ((unsigned short*)Outp)[(size_t)(row + e) * DM + col] = f2bf(v);
        else
          ((float*)Outp)[(size_t)(row + e) * DM + col] = v;
      }
    }
  }
}

// ---------------- attention: 8 waves x 16 q-rows, swapped QK^T, exp2 softmax ----------
__global__ __launch_bounds__(512) void attn_k(const unsigned short* __restrict__ qp,
                                              const unsigned short* __restrict__ kp,
                                              const unsigned short* __restrict__ vp,
                                              const float* __restrict__ mm,
                                              unsigned short* __restrict__ xout) {
  __shared__ char smem[32768];
  // [0,16384): ks [128][64] bf16, 16B-granule XOR swizzle (gi ^= row&7); after
  //            the post-QK^T barrier, reused as ps [128][64] bf16 COLUMN-HALF
  //            of P (two passes: cols 0..63 then 64..127), 8B granules,
  //            gi ^= (q&3)<<2.
  // [16384,32768): vt [64][128] bf16, 4-elem granule swizzle: phys = kq ^ ((d>>3)<<2)
  unsigned short* vt = (unsigned short*)(smem + 16384);

  const int tid = threadIdx.x, lane = tid & 63, wid = tid >> 6;
  const int cl = lane & 15, g = lane >> 4;
  const int h = blockIdx.x, l = blockIdx.y;
  const size_t base = (size_t)l * 128 * DM + h * 64;
  const int q = wid * 16 + cl;                   // this lane's q-row

#pragma unroll
  for (int p = 0; p < 2; ++p) {
    const int chunk = p * 8 + wid;              // 0..15, 1KB each
    const int row = chunk * 8 + (lane >> 3);    // 128B rows
    const int gi = (lane & 7) ^ (row & 7);
    gl_lds16(kp + base + (size_t)row * DM + gi * 8, smem + chunk * 1024);
  }
  if (tid < 256) {
    const int dc = (tid & 7) * 8;
    const int kq = tid >> 3;
    const int pg = (kq ^ ((tid & 7) << 2));
    int4 r0 = *(const int4*)&vp[base + (size_t)(kq * 4 + 0) * DM + dc];
    int4 r1 = *(const int4*)&vp[base + (size_t)(kq * 4 + 1) * DM + dc];
    int4 r2 = *(const int4*)&vp[base + (size_t)(kq * 4 + 2) * DM + dc];
    int4 r3 = *(const int4*)&vp[base + (size_t)(kq * 4 + 3) * DM + dc];
    const unsigned short* u0 = (const unsigned short*)&r0;
    const unsigned short* u1 = (const unsigned short*)&r1;
    const unsigned short* u2 = (const unsigned short*)&r2;
    const unsigned short* u3 = (const unsigned short*)&r3;
#pragma unroll
    for (int j = 0; j < 8; ++j) {
      ushort4 w = {u0[j], u1[j], u2[j], u3[j]};
      *(ushort4*)&vt[(dc + j) * 128 + pg * 4] = w;
    }
  }
  bf16x8 qf[2];
#pragma unroll
  for (int ksr = 0; ksr < 2; ++ksr)
    qf[ksr] = *(const bf16x8*)&qp[base + (size_t)q * DM + ksr * 32 + g * 8];
  __syncthreads();

  f32x4 sacc[8] = {};
  __builtin_amdgcn_s_setprio(1);
#pragma unroll
  for (int ksr = 0; ksr < 2; ++ksr) {
#pragma unroll
    for (int kf = 0; kf < 8; ++kf) {
      const int row = kf * 16 + cl;
      const int gi = (ksr * 4 + g) ^ (row & 7);
      bf16x8 kfr = *(const bf16x8*)(smem + row * 128 + gi * 16);
      sacc[kf] = __builtin_amdgcn_mfma_f32_16x16x32_bf16(kfr, qf[ksr], sacc[kf], 0, 0, 0);
    }
  }
  __builtin_amdgcn_s_setprio(0);
  __syncthreads();   // all waves' ks reads done before any ps write (ps aliases ks)

  // ---- dual softmax, exp2-folded, no max subtraction (inputs bounded)
  bf16x4 pk[8];
  {
    float4 mrow[8];
#pragma unroll
    for (int kf = 0; kf < 8; ++kf)
      mrow[kf] = *(const float4*)&mm[q * 128 + kf * 16 + g * 4];
    float sm = 0.f;
#pragma unroll
    for (int kf = 0; kf < 8; ++kf)
#pragma unroll
      for (int e = 0; e < 4; ++e) {
        float p = exp2f(sacc[kf][e] * (0.125f * LOG2E));   // = exp(s/8)
        sacc[kf][e] = p;
        sm += p;
      }
    sm += __shfl_xor(sm, 16); sm += __shfl_xor(sm, 32);
    const float inv2e = LOG2E / sm;
    float s2 = 0.f;
#pragma unroll
    for (int kf = 0; kf < 8; ++kf)
#pragma unroll
      for (int e = 0; e < 4; ++e) {
        // mrow prescaled by log2e: exp(p/sm + m) = exp2(p*inv2e + m*log2e)
        float p = exp2f(fmaf(sacc[kf][e], inv2e, ((const float*)&mrow[kf])[e]));
        sacc[kf][e] = p;
        s2 += p;
      }
    s2 += __shfl_xor(s2, 16); s2 += __shfl_xor(s2, 32);
    const float inv2 = 1.0f / s2;
#pragma unroll
    for (int kf = 0; kf < 8; ++kf)
      pk[kf] = {(__bf16)(sacc[kf][0] * inv2), (__bf16)(sacc[kf][1] * inv2),
                (__bf16)(sacc[kf][2] * inv2), (__bf16)(sacc[kf][3] * inv2)};
  }

  // ---- PV in two column-halves through the 16KB ps buffer (wave-local rows;
  // lgkm fences only, no block barrier; rule #18 sched_barrier after each).
  f32x4 xacc[4] = {};
#pragma unroll
  for (int half = 0; half < 2; ++half) {
#pragma unroll
    for (int kf = 0; kf < 4; ++kf) {
      const int gi = (kf * 4 + g) ^ ((q & 3) << 2);
      *(bf16x4*)(smem + q * 128 + gi * 8) = pk[half * 4 + kf];
    }
    asm volatile("s_waitcnt lgkmcnt(0)" ::: "memory");
    __builtin_amdgcn_sched_barrier(0);
    __builtin_amdgcn_s_setprio(1);
#pragma unroll
    for (int k2 = 0; k2 < 2; ++k2) {
      const int ks2 = half * 2 + k2;
      const int gi = (k2 * 8 + g * 2) ^ ((q & 3) << 2);
      bf16x8 pa = *(const bf16x8*)(smem + q * 128 + gi * 8);
#pragma unroll
      for (int fc = 0; fc < 4; ++fc) {
        const int d = fc * 16 + cl;
        const int pg = (ks2 * 8 + 2 * g) ^ (((d >> 3) & 7) << 2);
        bf16x8 bv = *(const bf16x8*)&vt[d * 128 + pg * 4];
        xacc[fc] = __builtin_amdgcn_mfma_f32_16x16x32_bf16(pa, bv, xacc[fc], 0, 0, 0);
      }
    }
    __builtin_amdgcn_s_setprio(0);
    if (half == 0) {
      asm volatile("s_waitcnt lgkmcnt(0)" ::: "memory");   // half-0 reads drained
      __builtin_amdgcn_sched_barrier(0);
    }
  }

  // X-store via plain casts (compiler cvt_pk where possible)
#pragma unroll
  for (int fc = 0; fc < 4; ++fc)
#pragma unroll
    for (int e = 0; e < 4; ++e) {
      const int qr = wid * 16 + g * 4 + e;
      __bf16 b = (__bf16)xacc[fc][e];
      unsigned short u;
      __builtin_memcpy(&u, &b, 2);
      xout[base + (size_t)qr * DM + fc * 16 + cl] = u;
    }
}

extern "C" void kernel_launch(void* const* d_in, const int* in_sizes, int n_in,
                              void* d_out, int out_size, void* d_ws, size_t ws_size,
                              hipStream_t stream) {
  (void)in_sizes; (void)n_in; (void)out_size; (void)ws_size;
  const float* Q = (const float*)d_in[0];
  const float* K = (const float*)d_in[1];
  const float* V = (const float*)d_in[2];
  const float* mask = (const float*)d_in[3];
  const float* Wq = (const float*)d_in[4];
  const float* bq = (const float*)d_in[5];
  const float* Wk = (const float*)d_in[6];
  const float* bk = (const float*)d_in[7];
  const float* Wv = (const float*)d_in[8];
  const float* bv = (const float*)d_in[9];
  const float* Wo = (const float*)d_in[10];
  const float* bo = (const float*)d_in[11];

  const size_t NP = (size_t)65536 * DM;   // elements per [65536][768] bf16 buffer

  unsigned short* qp = (unsigned short*)d_out;
  unsigned short* kp = qp + NP;
  unsigned short* S1 = (unsigned short*)d_ws;
  unsigned short* S2 = S1 + NP;
  unsigned short* wt = S2 + NP;                 // [4][768*768] bf16
  float* mm = (float*)(wt + (size_t)4 * DM * DM);

  prep_w<<<dim3(24, 24, 4), 256, 0, stream>>>(Wq, Wk, Wv, Wo, wt);
  prep_m<<<dim3(128), 64, 0, stream>>>(mask, mm);

  const int n8 = (int)(NP / 8);
  dim3 g8(768);

  convb<<<dim3(2048), 256, 0, stream>>>(Q, S1, n8);
  gemm8<true><<<g8, 512, 0, stream>>>(S1, wt + 0 * (size_t)DM * DM, bq, qp);
  convb<<<dim3(2048), 256, 0, stream>>>(K, S1, n8);
  gemm8<true><<<g8, 512, 0, stream>>>(S1, wt + 1 * (size_t)DM * DM, bk, kp);
  convb<<<dim3(2048), 256, 0, stream>>>(V, S2, n8);
  gemm8<true><<<g8, 512, 0, stream>>>(S2, wt + 2 * (size_t)DM * DM, bv, S1);

  attn_k<<<dim3(12, 512), 512, 0, stream>>>(qp, kp, S1, mm, S1);

  gemm8<false><<<g8, 512, 0, stream>>>(S1, wt + 3 * (size_t)DM * DM, bo, (float*)d_out);
}

// Round 5
// 662.405 us; speedup vs baseline: 1.1474x; 1.1087x over previous
//
#include <hip/hip_runtime.h>

// MultiHeadedAttention: out = ((softmax(softmax(QK^T/8)+softmax(mask/128)))V) @ Wo
// Q,K,V (128,512,768) fp32 -> flat [65536][768]. Attention slice (l,h) = rows
// l*128..+127, cols h*64..+63 of the flat projection buffers.
// R4 post-mortem: paired K-steps regressed gemm8 (97->115us) -> sync frequency
// exonerated; R1 fine interleave restored EXACTLY (proven 662.7us total).
// This round (single variable): fix the vt bank swizzle in attn_k. Old PV read
// pg = (ks2*8+2g)^(((d>>3)&7)<<2): (d>>3)>>1 = fc is lane-invariant per instr
// -> 64 lanes hit only 16 of 32 banks (2x serialization on 16 b128/thread).
// New layout: 16B granules, pgk = (k>>3) ^ (((d>>3)&1)<<2); read spans cover
// all 32 banks evenly (8 dwords/bank = b128 floor), write spans 16 distinct
// 2-dword starts (4 dwords/bank = 8B-write floor). Bijective, 3 lines changed.
//   convb: fp32->bf16 L3-staging. gemm8: R1 cross-phase ds_read prefetch,
//   vmcnt 6/4/0. attn: R1 (32KB, ps column-halves, exp2-folded dual softmax).

typedef __attribute__((ext_vector_type(8))) __bf16 bf16x8;
typedef __attribute__((ext_vector_type(4))) __bf16 bf16x4;
typedef __attribute__((ext_vector_type(4))) float f32x4;

#define DM 768
#define LOG2E 1.44269504f

__device__ __forceinline__ unsigned short f2bf(float x) {
  unsigned u = __float_as_uint(x);
  u += 0x7FFFu + ((u >> 16) & 1u);   // RNE
  return (unsigned short)(u >> 16);
}

__device__ __forceinline__ void gl_lds16(const void* g, void* l) {
  __builtin_amdgcn_global_load_lds(
      (const __attribute__((address_space(1))) unsigned int*)g,
      (__attribute__((address_space(3))) unsigned int*)l, 16, 0, 0);
}

// ---------------- prep: transpose+convert 4 weights to bf16 [op][n][k] ----------------
__global__ __launch_bounds__(256) void prep_w(const float* __restrict__ w0,
                                              const float* __restrict__ w1,
                                              const float* __restrict__ w2,
                                              const float* __restrict__ w3,
                                              unsigned short* __restrict__ wt) {
  __shared__ float t[32][33];
  const int op = blockIdx.z;
  const float* w = (op == 0) ? w0 : (op == 1) ? w1 : (op == 2) ? w2 : w3;
  unsigned short* o = wt + (size_t)op * DM * DM;
  const int n0 = blockIdx.x * 32, k0 = blockIdx.y * 32;
  const int tx = threadIdx.x & 31, ty = threadIdx.x >> 5;   // ty 0..7
#pragma unroll
  for (int r = 0; r < 4; ++r)
    t[r * 8 + ty][tx] = w[(size_t)(k0 + r * 8 + ty) * DM + n0 + tx];
  __syncthreads();
#pragma unroll
  for (int r = 0; r < 4; ++r)
    o[(size_t)(n0 + r * 8 + ty) * DM + k0 + tx] = f2bf(t[tx][r * 8 + ty]);
}

// ------- prep: mm = softmax(mask/128, axis=-1) * log2e, fp32 [128][128] ---------------
__global__ void prep_m(const float* __restrict__ mask, float* __restrict__ mm) {
  int row = blockIdx.x;
  int t = threadIdx.x;  // 64 threads
  float a = mask[row * 128 + t] * (1.0f / 128.0f);
  float b = mask[row * 128 + t + 64] * (1.0f / 128.0f);
  float mx = fmaxf(a, b);
  for (int s = 1; s < 64; s <<= 1) mx = fmaxf(mx, __shfl_xor(mx, s));
  float ea = __expf(a - mx), eb = __expf(b - mx);
  float sum = ea + eb;
  for (int s = 1; s < 64; s <<= 1) sum += __shfl_xor(sum, s);
  float inv = LOG2E / sum;               // prescale by log2e for attn's exp2 path
  mm[row * 128 + t] = ea * inv;
  mm[row * 128 + t + 64] = eb * inv;
}

// ---------------- conv: fp32 -> bf16, vectorized (8 elems/thread/iter) ----------------
__global__ __launch_bounds__(256) void convb(const float* __restrict__ in,
                                             unsigned short* __restrict__ out, int n8) {
  int i = blockIdx.x * 256 + threadIdx.x;
  const int stride = gridDim.x * 256;
  for (; i < n8; i += stride) {
    const float4 a = ((const float4*)in)[(size_t)i * 2];
    const float4 b = ((const float4*)in)[(size_t)i * 2 + 1];
    ushort4 lo = {f2bf(a.x), f2bf(a.y), f2bf(a.z), f2bf(a.w)};
    ushort4 hi = {f2bf(b.x), f2bf(b.y), f2bf(b.z), f2bf(b.w)};
    ((ushort4*)out)[(size_t)i * 2] = lo;
    ((ushort4*)out)[(size_t)i * 2 + 1] = hi;
  }
}

// ---------------- gemm8: [65536 x 768] bf16 A @ [768 x 768] Bt(n-major bf16) ----------
__device__ __forceinline__ void stage_tile(const unsigned short* __restrict__ src,
                                           int row0, int kcol, char* slotbase, int tid) {
  const int wid = tid >> 6, lane = tid & 63;
#pragma unroll
  for (int s = 0; s < 2; ++s) {
    const int row = s * 128 + wid * 16 + (lane >> 2);
    const int slot = lane & 3;
    gl_lds16(src + (size_t)(row0 + row) * DM + kcol + ((slot ^ ((row >> 1) & 3)) * 8),
             slotbase + s * 8192 + wid * 1024);
  }
}

template <bool OUT_BF16>
__global__ __launch_bounds__(512, 2) void gemm8(const unsigned short* __restrict__ A,
                                                const unsigned short* __restrict__ Bt,
                                                const float* __restrict__ bias,
                                                void* __restrict__ Outp) {
  __shared__ char smem[131072];   // A ring 4x16KB @0, B ring 4x16KB @65536
  const int tid = threadIdx.x, lane = tid & 63, wid = tid >> 6;
  const int cl = lane & 15, g = lane >> 4;
  const int wm = wid >> 2, wn = wid & 3;
  const int bid = blockIdx.x;
  const int xcd = bid & 7, bi = bid >> 3;        // 768 = 8 xcd * (32 m * 3 n)
  const int m0 = (xcd * 32 + bi / 3) * 256;
  const int n0 = (bi % 3) * 256;

  f32x4 acc[8][4] = {};

  auto aslot = [&](int t) { return (char*)smem + (t & 3) * 16384; };
  auto bslot = [&](int t) { return (char*)smem + 65536 + (t & 3) * 16384; };

  auto lda = [&](bf16x8* af, int t, int half) {
#pragma unroll
    for (int mi = 0; mi < 4; ++mi) {
      const int r = wm * 128 + (half * 4 + mi) * 16 + cl;
      af[mi] = *(const bf16x8*)(aslot(t) + r * 64 + ((g ^ ((r >> 1) & 3)) * 16));
    }
  };
  auto ldb = [&](bf16x8* bf, int t) {
#pragma unroll
    for (int ni = 0; ni < 4; ++ni) {
      const int r = wn * 64 + ni * 16 + cl;
      bf[ni] = *(const bf16x8*)(bslot(t) + r * 64 + ((g ^ ((r >> 1) & 3)) * 16));
    }
  };
  auto mfma16 = [&](bf16x8* af, bf16x8* bf, int half) {
    __builtin_amdgcn_s_setprio(1);
#pragma unroll
    for (int mi = 0; mi < 4; ++mi)
#pragma unroll
      for (int ni = 0; ni < 4; ++ni)
        acc[half * 4 + mi][ni] = __builtin_amdgcn_mfma_f32_16x16x32_bf16(
            af[mi], bf[ni], acc[half * 4 + mi][ni], 0, 0, 0);
    __builtin_amdgcn_s_setprio(0);
  };

  // One K-step with cross-phase prefetch. Entering: (af0, bfc) hold step-t frags.
  // ph0: stage A(t+3); drain vmcnt so B(t+1) landed (all waves) -> barrier;
  //      issue af1 reads; MFMA half0 (overlaps af1 reads).
  // ph1: stage B(t+3); issue (t+1) frag reads (slot sealed by ph0 barrier);
  //      MFMA half1 (overlaps t+1 reads); end barrier (seals slot reuse WAR).
  auto gstep = [&](int t, bool stg, int vm, bf16x8* af0, bf16x8* bfc,
                   bf16x8* af0n, bf16x8* bfn, bool last) {
    bf16x8 af1[4];
    if (stg) stage_tile(A, m0, (t + 3) * 32, aslot(t + 3), tid);
    if (vm == 6)      asm volatile("s_waitcnt vmcnt(6)" ::: "memory");
    else if (vm == 4) asm volatile("s_waitcnt vmcnt(4)" ::: "memory");
    else              asm volatile("s_waitcnt vmcnt(0)" ::: "memory");
    __builtin_amdgcn_s_barrier();
    lda(af1, t, 1);                       // ds reads overlap half0 MFMAs
    mfma16(af0, bfc, 0);
    if (stg) stage_tile(Bt, n0, (t + 3) * 32, bslot(t + 3), tid);
    if (!last) {
      lda(af0n, t + 1, 0);                // ds reads overlap half1 MFMAs
      ldb(bfn, t + 1);
    }
    mfma16(af1, bfc, 1);
    __builtin_amdgcn_s_barrier();
  };

  // prologue: tiles 0,1,2 staged; tile 0 landed; preload step-0 frags.
  stage_tile(A, m0, 0, aslot(0), tid);   stage_tile(Bt, n0, 0, bslot(0), tid);
  stage_tile(A, m0, 32, aslot(1), tid);  stage_tile(Bt, n0, 32, bslot(1), tid);
  stage_tile(A, m0, 64, aslot(2), tid);  stage_tile(Bt, n0, 64, bslot(2), tid);
  asm volatile("s_waitcnt vmcnt(8)" ::: "memory");   // A0,B0 landed
  __builtin_amdgcn_s_barrier();

  bf16x8 afA[4], bfA[4], afB[4], bfB[4];
  lda(afA, 0, 0);
  ldb(bfA, 0);

#pragma unroll 1
  for (int t = 0; t < 20; t += 2) {
    gstep(t, true, 6, afA, bfA, afB, bfB, false);
    gstep(t + 1, true, 6, afB, bfB, afA, bfA, false);
  }
  gstep(20, true, 6, afA, bfA, afB, bfB, false);
  gstep(21, false, 4, afB, bfB, afA, bfA, false);
  gstep(22, false, 0, afA, bfA, afB, bfB, false);
  gstep(23, false, 0, afB, bfB, afA, bfA, true);

  float bb[4];
#pragma unroll
  for (int ni = 0; ni < 4; ++ni) bb[ni] = bias[n0 + wn * 64 + ni * 16 + cl];
#pragma unroll
  for (int mi = 0; mi < 8; ++mi) {
    const int row = m0 + wm * 128 + mi * 16 + g * 4;
#pragma unroll
    for (int ni = 0; ni < 4; ++ni) {
      const int col = n0 + wn * 64 + ni * 16 + cl;
#pragma unroll
      for (int e = 0; e < 4; ++e) {
        float v = acc[mi][ni][e] + bb[ni];
        if constexpr (OUT_BF16)
          ((unsigned short*)Outp)[(size_t)(row + e) * DM + col] = f2bf(v);
        else
          ((float*)Outp)[(size_t)(row + e) * DM + col] = v;
      }
    }
  }
}

// ---------------- attention: 8 waves x 16 q-rows, swapped QK^T, exp2 softmax ----------
__global__ __launch_bounds__(512) void attn_k(const unsigned short* __restrict__ qp,
                                              const unsigned short* __restrict__ kp,
                                              const unsigned short* __restrict__ vp,
                                              const float* __restrict__ mm,
                                              unsigned short* __restrict__ xout) {
  __shared__ char smem[32768];
  // [0,16384): ks [128][64] bf16, 16B-granule XOR swizzle (gi ^= row&7); after
  //            the post-QK^T barrier, reused as ps [128][64] bf16 COLUMN-HALF
  //            of P (two passes: cols 0..63 then 64..127), 8B granules,
  //            gi ^= (q&3)<<2.
  // [16384,32768): vt [64][128] bf16. 16B physical granules: logical elem
  //            (d, k) lives at d*128 + pgk*8 + (k&7), pgk = (k>>3) ^
  //            (((d>>3)&1)<<2). Read spans cover 32 banks (8 dwords/bank,
  //            b128 floor); write spans 16 distinct 2-dword starts (4/bank).
  unsigned short* vt = (unsigned short*)(smem + 16384);

  const int tid = threadIdx.x, lane = tid & 63, wid = tid >> 6;
  const int cl = lane & 15, g = lane >> 4;
  const int h = blockIdx.x, l = blockIdx.y;
  const size_t base = (size_t)l * 128 * DM + h * 64;
  const int q = wid * 16 + cl;                   // this lane's q-row

#pragma unroll
  for (int p = 0; p < 2; ++p) {
    const int chunk = p * 8 + wid;              // 0..15, 1KB each
    const int row = chunk * 8 + (lane >> 3);    // 128B rows
    const int gi = (lane & 7) ^ (row & 7);
    gl_lds16(kp + base + (size_t)row * DM + gi * 8, smem + chunk * 1024);
  }
  if (tid < 256) {
    const int dc = (tid & 7) * 8;
    const int kq = tid >> 3;                    // k-granule of 4 elems, 0..31
    int4 r0 = *(const int4*)&vp[base + (size_t)(kq * 4 + 0) * DM + dc];
    int4 r1 = *(const int4*)&vp[base + (size_t)(kq * 4 + 1) * DM + dc];
    int4 r2 = *(const int4*)&vp[base + (size_t)(kq * 4 + 2) * DM + dc];
    int4 r3 = *(const int4*)&vp[base + (size_t)(kq * 4 + 3) * DM + dc];
    const unsigned short* u0 = (const unsigned short*)&r0;
    const unsigned short* u1 = (const unsigned short*)&r1;
    const unsigned short* u2 = (const unsigned short*)&r2;
    const unsigned short* u3 = (const unsigned short*)&r3;
    // pgk = (k>>3) ^ (((d>>3)&1)<<2); here d>>3 = tid&7 (dc=(tid&7)*8, j<8)
    const int pg = (kq >> 1) ^ ((tid & 1) << 2);
    const int ofs = (kq & 1) * 4;               // half-granule offset (elems)
#pragma unroll
    for (int j = 0; j < 8; ++j) {
      ushort4 w = {u0[j], u1[j], u2[j], u3[j]};
      *(ushort4*)&vt[(dc + j) * 128 + pg * 8 + ofs] = w;
    }
  }
  bf16x8 qf[2];
#pragma unroll
  for (int ksr = 0; ksr < 2; ++ksr)
    qf[ksr] = *(const bf16x8*)&qp[base + (size_t)q * DM + ksr * 32 + g * 8];
  __syncthreads();

  f32x4 sacc[8] = {};
  __builtin_amdgcn_s_setprio(1);
#pragma unroll
  for (int ksr = 0; ksr < 2; ++ksr) {
#pragma unroll
    for (int kf = 0; kf < 8; ++kf) {
      const int row = kf * 16 + cl;
      const int gi = (ksr * 4 + g) ^ (row & 7);
      bf16x8 kfr = *(const bf16x8*)(smem + row * 128 + gi * 16);
      sacc[kf] = __builtin_amdgcn_mfma_f32_16x16x32_bf16(kfr, qf[ksr], sacc[kf], 0, 0, 0);
    }
  }
  __builtin_amdgcn_s_setprio(0);
  __syncthreads();   // all waves' ks reads done before any ps write (ps aliases ks)

  // ---- dual softmax, exp2-folded, no max subtraction (inputs bounded)
  bf16x4 pk[8];
  {
    float4 mrow[8];
#pragma unroll
    for (int kf = 0; kf < 8; ++kf)
      mrow[kf] = *(const float4*)&mm[q * 128 + kf * 16 + g * 4];
    float sm = 0.f;
#pragma unroll
    for (int kf = 0; kf < 8; ++kf)
#pragma unroll
      for (int e = 0; e < 4; ++e) {
        float p = exp2f(sacc[kf][e] * (0.125f * LOG2E));   // = exp(s/8)
        sacc[kf][e] = p;
        sm += p;
      }
    sm += __shfl_xor(sm, 16); sm += __shfl_xor(sm, 32);
    const float inv2e = LOG2E / sm;
    float s2 = 0.f;
#pragma unroll
    for (int kf = 0; kf < 8; ++kf)
#pragma unroll
      for (int e = 0; e < 4; ++e) {
        // mrow prescaled by log2e: exp(p/sm + m) = exp2(p*inv2e + m*log2e)
        float p = exp2f(fmaf(sacc[kf][e], inv2e, ((const float*)&mrow[kf])[e]));
        sacc[kf][e] = p;
        s2 += p;
      }
    s2 += __shfl_xor(s2, 16); s2 += __shfl_xor(s2, 32);
    const float inv2 = 1.0f / s2;
#pragma unroll
    for (int kf = 0; kf < 8; ++kf)
      pk[kf] = {(__bf16)(sacc[kf][0] * inv2), (__bf16)(sacc[kf][1] * inv2),
                (__bf16)(sacc[kf][2] * inv2), (__bf16)(sacc[kf][3] * inv2)};
  }

  // ---- PV in two column-halves through the 16KB ps buffer (wave-local rows;
  // lgkm fences only, no block barrier; rule #18 sched_barrier after each).
  f32x4 xacc[4] = {};
#pragma unroll
  for (int half = 0; half < 2; ++half) {
#pragma unroll
    for (int kf = 0; kf < 4; ++kf) {
      const int gi = (kf * 4 + g) ^ ((q & 3) << 2);
      *(bf16x4*)(smem + q * 128 + gi * 8) = pk[half * 4 + kf];
    }
    asm volatile("s_waitcnt lgkmcnt(0)" ::: "memory");
    __builtin_amdgcn_sched_barrier(0);
    __builtin_amdgcn_s_setprio(1);
#pragma unroll
    for (int k2 = 0; k2 < 2; ++k2) {
      const int ks2 = half * 2 + k2;
      const int gi = (k2 * 8 + g * 2) ^ ((q & 3) << 2);
      bf16x8 pa = *(const bf16x8*)(smem + q * 128 + gi * 8);
#pragma unroll
      for (int fc = 0; fc < 4; ++fc) {
        const int d = fc * 16 + cl;
        // vt read: one full 16B granule; pgk = (k>>3) ^ (((d>>3)&1)<<2),
        // (d>>3)&1 = cl>>3 varies per lane -> all 32 banks covered.
        const int pg = (ks2 * 4 + g) ^ (((d >> 3) & 1) << 2);
        bf16x8 bv = *(const bf16x8*)&vt[d * 128 + pg * 8];
        xacc[fc] = __builtin_amdgcn_mfma_f32_16x16x32_bf16(pa, bv, xacc[fc], 0, 0, 0);
      }
    }
    __builtin_amdgcn_s_setprio(0);
    if (half == 0) {
      asm volatile("s_waitcnt lgkmcnt(0)" ::: "memory");   // half-0 reads drained
      __builtin_amdgcn_sched_barrier(0);
    }
  }

  // X-store via plain casts (compiler cvt_pk where possible)
#pragma unroll
  for (int fc = 0; fc < 4; ++fc)
#pragma unroll
    for (int e = 0; e < 4; ++e) {
      const int qr = wid * 16 + g * 4 + e;
      __bf16 b = (__bf16)xacc[fc][e];
      unsigned short u;
      __builtin_memcpy(&u, &b, 2);
      xout[base + (size_t)qr * DM + fc * 16 + cl] = u;
    }
}

extern "C" void kernel_launch(void* const* d_in, const int* in_sizes, int n_in,
                              void* d_out, int out_size, void* d_ws, size_t ws_size,
                              hipStream_t stream) {
  (void)in_sizes; (void)n_in; (void)out_size; (void)ws_size;
  const float* Q = (const float*)d_in[0];
  const float* K = (const float*)d_in[1];
  const float* V = (const float*)d_in[2];
  const float* mask = (const float*)d_in[3];
  const float* Wq = (const float*)d_in[4];
  const float* bq = (const float*)d_in[5];
  const float* Wk = (const float*)d_in[6];
  const float* bk = (const float*)d_in[7];
  const float* Wv = (const float*)d_in[8];
  const float* bv = (const float*)d_in[9];
  const float* Wo = (const float*)d_in[10];
  const float* bo = (const float*)d_in[11];

  const size_t NP = (size_t)65536 * DM;   // elements per [65536][768] bf16 buffer

  unsigned short* qp = (unsigned short*)d_out;
  unsigned short* kp = qp + NP;
  unsigned short* S1 = (unsigned short*)d_ws;
  unsigned short* S2 = S1 + NP;
  unsigned short* wt = S2 + NP;                 // [4][768*768] bf16
  float* mm = (float*)(wt + (size_t)4 * DM * DM);

  prep_w<<<dim3(24, 24, 4), 256, 0, stream>>>(Wq, Wk, Wv, Wo, wt);
  prep_m<<<dim3(128), 64, 0, stream>>>(mask, mm);

  const int n8 = (int)(NP / 8);
  dim3 g8(768);

  convb<<<dim3(2048), 256, 0, stream>>>(Q, S1, n8);
  gemm8<true><<<g8, 512, 0, stream>>>(S1, wt + 0 * (size_t)DM * DM, bq, qp);
  convb<<<dim3(2048), 256, 0, stream>>>(K, S1, n8);
  gemm8<true><<<g8, 512, 0, stream>>>(S1, wt + 1 * (size_t)DM * DM, bk, kp);
  convb<<<dim3(2048), 256, 0, stream>>>(V, S2, n8);
  gemm8<true><<<g8, 512, 0, stream>>>(S2, wt + 2 * (size_t)DM * DM, bv, S1);

  attn_k<<<dim3(12, 512), 512, 0, stream>>>(qp, kp, S1, mm, S1);

  gemm8<false><<<g8, 512, 0, stream>>>(S1, wt + 3 * (size_t)DM * DM, bo, (float*)d_out);
}